// Round 4
// baseline (715.580 us; speedup 1.0000x reference)
//
#include <hip/hip_runtime.h>
#include <stdint.h>

#define T_TOK 32768
#define H_DIM 576
#define I_DIM 512
#define NEXP 8
#define WELEM 294912  // 576*512 elements per expert weight matrix

// block ranges
#define NB_CVTX 4608
#define NB_WHI 5184
#define NB_WIH 2592
#define NB_RT 1024
#define NB_SGU 1024   // shared gateup: 256 mb x 4 nb
#define NB_SDN 1280   // shared down: 256 mb x 5 nb
#define NB_PGU 1056   // phase gateup: 264 mb x 4 nb
#define NB_PDN 1320   // phase down: 264 mb x 5 nb
#define NB_SC 64      // scatter: 64 blocks x 512 threads

typedef __attribute__((ext_vector_type(8))) short short8;
typedef __attribute__((ext_vector_type(4))) float f32x4;
typedef __attribute__((ext_vector_type(4))) float f4;
typedef __attribute__((ext_vector_type(4))) unsigned short u16x4;

__device__ __forceinline__ unsigned short f2bf(float f) {
  union { float f; unsigned u; } v; v.f = f;
  unsigned r = (v.u + 0x7fffu + ((v.u >> 16) & 1u)) >> 16;
  return (unsigned short)r;
}

__device__ __forceinline__ void gl16(const void* g, void* l) {
  __builtin_amdgcn_global_load_lds(
      (const __attribute__((address_space(1))) unsigned*)g,
      (__attribute__((address_space(3))) unsigned*)l, 16, 0, 0);
}

// ================= K1: cvt_x || cvt_w(HI) || cvt_w(IH) || router =============

__global__ __launch_bounds__(256) void prep_k(
    const float* __restrict__ x, unsigned short* __restrict__ xb,
    const float* __restrict__ sgw, const float* __restrict__ suw,
    const float* __restrict__ rgw, const float* __restrict__ ruw,
    unsigned short* __restrict__ wsg, unsigned short* __restrict__ wsu,
    unsigned short* __restrict__ wrg, unsigned short* __restrict__ wru,
    const float* __restrict__ sdw, const float* __restrict__ rdw,
    unsigned short* __restrict__ wsd, unsigned short* __restrict__ wrd,
    const float* __restrict__ rw, const float* __restrict__ rb,
    int* __restrict__ tki, float* __restrict__ tkw, int* __restrict__ counts) {
  __shared__ float tile[32][33];
  __shared__ int hist[16];
  int b = blockIdx.x, tid = threadIdx.x;
  if (b < NB_CVTX) {
    // ---- cvt_x: 4.72M float4 slots, 4 iters ----
    size_t base = (size_t)b * 256 + tid;
#pragma unroll
    for (int it = 0; it < 4; it++) {
      size_t i = (base + (size_t)it * NB_CVTX * 256) * 4;
      f4 v = *(const f4*)(x + i);
      u16x4 o;
      o.x = f2bf(v.x); o.y = f2bf(v.y); o.z = f2bf(v.z); o.w = f2bf(v.w);
      *(u16x4*)(xb + i) = o;
    }
  } else if (b < NB_CVTX + NB_WHI) {
    // ---- [576][512] -> [512][576] bf16; z0=sgw z1=suw z2-9=rgw z10-17=ruw ----
    int b2 = b - NB_CVTX;
    int z = b2 / 288, r = b2 % 288, bx = r & 15, by = r >> 4;
    int tx = tid & 31, ty = tid >> 5;
    const float* src; unsigned short* dst;
    if (z == 0)      { src = sgw;                            dst = wsg; }
    else if (z == 1) { src = suw;                            dst = wsu; }
    else if (z < 10) { src = rgw + (size_t)(z - 2) * WELEM;  dst = wrg + (size_t)(z - 2) * WELEM; }
    else             { src = ruw + (size_t)(z - 10) * WELEM; dst = wru + (size_t)(z - 10) * WELEM; }
    int r0 = by * 32, c0 = bx * 32;
    for (int i = ty; i < 32; i += 8)
      tile[i][tx] = src[(size_t)(r0 + i) * 512 + c0 + tx];
    __syncthreads();
    for (int i = ty; i < 32; i += 8)
      dst[(size_t)(c0 + i) * 576 + r0 + tx] = f2bf(tile[tx][i]);
  } else if (b < NB_CVTX + NB_WHI + NB_WIH) {
    // ---- [512][576] -> [576][512] bf16; z0=sdw z1-8=rdw ----
    int b3 = b - NB_CVTX - NB_WHI;
    int z = b3 / 288, r = b3 % 288, bx = r % 18, by = r / 18;
    int tx = tid & 31, ty = tid >> 5;
    const float* src = (z == 0) ? sdw : rdw + (size_t)(z - 1) * WELEM;
    unsigned short* dst = (z == 0) ? wsd : wrd + (size_t)(z - 1) * WELEM;
    int r0 = by * 32, c0 = bx * 32;
    for (int i = ty; i < 32; i += 8)
      tile[i][tx] = src[(size_t)(r0 + i) * 576 + c0 + tx];
    __syncthreads();
    for (int i = ty; i < 32; i += 8)
      dst[(size_t)(c0 + i) * 512 + r0 + tx] = f2bf(tile[tx][i]);
  } else {
    // ---- router: 8 lanes/token, 72-elem H-slices, fp32 exact ----
    int rblk = b - NB_CVTX - NB_WHI - NB_WIH;
    int wv = tid >> 6, lane = tid & 63, tk = lane >> 3, sl = lane & 7;
    int t = rblk * 32 + wv * 8 + tk;
    if (tid < 16) hist[tid] = 0;
    const float* xr = x + (size_t)t * H_DIM + sl * 72;
    const float* rwp = rw + sl * 72 * NEXP;
    float acc[NEXP];
#pragma unroll
    for (int e = 0; e < NEXP; e++) acc[e] = 0.f;
    for (int hh = 0; hh < 72; hh += 4) {
      f4 xv = *(const f4*)(xr + hh);
#pragma unroll
      for (int j = 0; j < 4; j++) {
        f4 w0 = *(const f4*)(rwp + (hh + j) * 8);
        f4 w1 = *(const f4*)(rwp + (hh + j) * 8 + 4);
        float xs = xv[j];
        acc[0] += xs * w0.x; acc[1] += xs * w0.y;
        acc[2] += xs * w0.z; acc[3] += xs * w0.w;
        acc[4] += xs * w1.x; acc[5] += xs * w1.y;
        acc[6] += xs * w1.z; acc[7] += xs * w1.w;
      }
    }
#pragma unroll
    for (int off = 1; off < 8; off <<= 1)
#pragma unroll
      for (int e = 0; e < NEXP; e++) acc[e] += __shfl_xor(acc[e], off);
    __syncthreads();
    if (sl == 0) {
      float l[NEXP];
#pragma unroll
      for (int e = 0; e < NEXP; e++) l[e] = acc[e] + rb[e];
      int e0 = 0;
#pragma unroll
      for (int e = 1; e < NEXP; e++) if (l[e] > l[e0]) e0 = e;
      int e1 = -1;
#pragma unroll
      for (int e = 0; e < NEXP; e++) {
        if (e == e0) continue;
        if (e1 < 0 || l[e] > l[e1]) e1 = e;
      }
      float w0 = 1.f / (1.f + __expf(l[e1] - l[e0]));
      tki[t * 2] = e0; tki[t * 2 + 1] = e1;
      tkw[t * 2] = w0; tkw[t * 2 + 1] = 1.f - w0;
      atomicAdd(&hist[e0], 1);
      atomicAdd(&hist[8 + e1], 1);
    }
    __syncthreads();
    if (tid < 16) atomicAdd(&counts[tid * 32], hist[tid]);
  }
}

__global__ void offsets_k(const int* __restrict__ counts, int* __restrict__ offs16,
                          int* __restrict__ pcnt16, int* __restrict__ pinfo) {
  if (threadIdx.x == 0) {
    int o = 0;
    for (int s = 0; s < 16; s++) {
      int c = counts[s * 32];
      int pc = (c + 127) & ~127;
      offs16[s] = o; pcnt16[s] = pc;
      o += pc;
    }
    pinfo[0] = offs16[8];
    pinfo[1] = o - offs16[8];
  }
}

// ================= device bodies (512 threads) ================================

__device__ void scatter_body(int blk, const int* __restrict__ tki,
                             const float* __restrict__ tkw, const int* __restrict__ offs16,
                             int* __restrict__ cursor, int* __restrict__ etok,
                             float* __restrict__ ew, int* lds_i) {
  int* hist = lds_i; int* base = lds_i + 16; int* lcur = lds_i + 32;
  int tid = threadIdx.x;
  if (tid < 16) { hist[tid] = 0; lcur[tid] = 0; }
  __syncthreads();
  int t = blk * 512 + tid;
  int s0 = tki[t * 2], s1 = 8 + tki[t * 2 + 1];
  atomicAdd(&hist[s0], 1);
  atomicAdd(&hist[s1], 1);
  __syncthreads();
  if (tid < 16) base[tid] = atomicAdd(&cursor[tid * 32], hist[tid]);
  __syncthreads();
#pragma unroll
  for (int k = 0; k < 2; k++) {
    int s = (k == 0) ? s0 : s1;
    int r = atomicAdd(&lcur[s], 1);
    int slot = offs16[s] + base[s] + r;
    etok[slot] = t;
    ew[slot] = tkw[t * 2 + k];
  }
}

// fused gate/up GEMM + silu; shared=1: identity rows; else one k-phase p
__device__ void gu_body(int blk, int shared, int p,
    const unsigned short* __restrict__ xb, const unsigned short* __restrict__ wg,
    const unsigned short* __restrict__ wu, unsigned short* __restrict__ h,
    const int* __restrict__ etok, const int* __restrict__ offs16,
    const int* __restrict__ pcnt16, const int* __restrict__ pinfo,
    unsigned short* As, unsigned short* Bg, unsigned short* Bu) {
  int mb, nb;
  if (shared) { mb = blk & 255; nb = blk >> 8; }
  else        { mb = blk % 264; nb = blk / 264; }
  int nrows = shared ? T_TOK : pinfo[p];
  if (mb * 128 >= nrows) return;
  int row_lo = (!shared && p) ? pinfo[0] : 0;
  int t = threadIdx.x;
  int wv = t >> 6, lane = t & 63;
  int ar = t >> 2, seg = t & 3;
  int sg = seg ^ ((ar >> 1) & 3);
  int m0 = mb * 128 + ar;
  int tok0, e = 0;
  if (shared) {
    tok0 = m0;
  } else {
    int g = row_lo + m0;
    int s = 0;
#pragma unroll
    for (int i = 0; i < 15; i++) s += (g >= offs16[i] + pcnt16[i]) ? 1 : 0;
    e = s & 7;
    tok0 = etok[g];
    if (tok0 < 0) tok0 = 0;
  }
  const unsigned short* ga = xb + (size_t)tok0 * H_DIM + sg * 8;
  int n0 = nb * 128 + ar;
  const unsigned short* gg = wg + (size_t)e * WELEM + (size_t)n0 * H_DIM + sg * 8;
  const unsigned short* gu = wu + (size_t)e * WELEM + (size_t)n0 * H_DIM + sg * 8;
  char* lA = (char*)As + wv * 1024;
  char* lG = (char*)Bg + wv * 1024;
  char* lU = (char*)Bu + wv * 1024;
  int fr = lane & 15, fq = lane >> 4;
  int wm = (wv >> 2) * 64, wn = (wv & 3) * 32;
  f32x4 accg[4][2] = {};
  f32x4 accu[4][2] = {};
  for (int k0 = 0; k0 < H_DIM; k0 += 32) {
    gl16(ga + k0, lA);
    gl16(gg + k0, lG);
    gl16(gu + k0, lU);
    __syncthreads();
    short8 a[4], g[2], u[2];
#pragma unroll
    for (int i = 0; i < 4; i++) {
      int r = wm + i * 16 + fr;
      a[i] = *(const short8*)&As[r * 32 + (fq ^ ((r >> 1) & 3)) * 8];
    }
#pragma unroll
    for (int j = 0; j < 2; j++) {
      int r = wn + j * 16 + fr;
      int sw = (fq ^ ((r >> 1) & 3)) * 8;
      g[j] = *(const short8*)&Bg[r * 32 + sw];
      u[j] = *(const short8*)&Bu[r * 32 + sw];
    }
#pragma unroll
    for (int i = 0; i < 4; i++)
#pragma unroll
      for (int j = 0; j < 2; j++) {
        accg[i][j] = __builtin_amdgcn_mfma_f32_16x16x32_bf16(a[i], g[j], accg[i][j], 0, 0, 0);
        accu[i][j] = __builtin_amdgcn_mfma_f32_16x16x32_bf16(a[i], u[j], accu[i][j], 0, 0, 0);
      }
    __syncthreads();
  }
#pragma unroll
  for (int i = 0; i < 4; i++)
#pragma unroll
    for (int j = 0; j < 2; j++)
#pragma unroll
      for (int r = 0; r < 4; r++) {
        int row = mb * 128 + wm + i * 16 + fq * 4 + r;
        int col = nb * 128 + wn + j * 16 + fr;
        float gv = accg[i][j][r], uv = accu[i][j][r];
        float hv = (gv / (1.f + __expf(-gv))) * uv;
        h[(size_t)row * I_DIM + col] = f2bf(hv);
      }
}

// down GEMM; mode 0: direct store (shared); mode 1: phase-p scatter RMW
__device__ void down_body(int blk, int mode, int p,
    const unsigned short* __restrict__ hbuf, const unsigned short* __restrict__ wd,
    float* __restrict__ out, const int* __restrict__ etok, const float* __restrict__ ew,
    const int* __restrict__ offs16, const int* __restrict__ pcnt16,
    const int* __restrict__ pinfo, unsigned short* As, unsigned short* Bs) {
  int mb, nb;
  if (mode == 0) { mb = blk & 255; nb = blk >> 8; }
  else           { mb = blk % 264; nb = blk / 264; }
  int nrows = (mode == 0) ? T_TOK : pinfo[p];
  if (mb * 128 >= nrows) return;
  int row_lo = (mode && p) ? pinfo[0] : 0;
  int t = threadIdx.x;
  int wv = t >> 6, lane = t & 63;
  int ar = t >> 2, seg = t & 3;
  int sg = seg ^ ((ar >> 1) & 3);
  int e = 0;
  if (mode == 1) {
    int g = row_lo + mb * 128 + ar;
    int s = 0;
#pragma unroll
    for (int i = 0; i < 15; i++) s += (g >= offs16[i] + pcnt16[i]) ? 1 : 0;
    e = s & 7;
  }
  const unsigned short* ga = hbuf + (size_t)(mb * 128 + ar) * I_DIM + sg * 8;
  int n0 = nb * 128 + ar;
  if (n0 > H_DIM - 1) n0 = H_DIM - 1;
  const unsigned short* gb = wd + (size_t)e * WELEM + (size_t)n0 * I_DIM + sg * 8;
  char* lA = (char*)As + wv * 1024;
  char* lB = (char*)Bs + wv * 1024;
  int fr = lane & 15, fq = lane >> 4;
  int wm = (wv >> 2) * 64, wn = (wv & 3) * 32;
  f32x4 acc[4][2] = {};
  for (int k0 = 0; k0 < I_DIM; k0 += 32) {
    gl16(ga + k0, lA);
    gl16(gb + k0, lB);
    __syncthreads();
    short8 a[4], b2[2];
#pragma unroll
    for (int i = 0; i < 4; i++) {
      int r = wm + i * 16 + fr;
      a[i] = *(const short8*)&As[r * 32 + (fq ^ ((r >> 1) & 3)) * 8];
    }
#pragma unroll
    for (int j = 0; j < 2; j++) {
      int r = wn + j * 16 + fr;
      b2[j] = *(const short8*)&Bs[r * 32 + (fq ^ ((r >> 1) & 3)) * 8];
    }
#pragma unroll
    for (int i = 0; i < 4; i++)
#pragma unroll
      for (int j = 0; j < 2; j++)
        acc[i][j] = __builtin_amdgcn_mfma_f32_16x16x32_bf16(a[i], b2[j], acc[i][j], 0, 0, 0);
    __syncthreads();
  }
#pragma unroll
  for (int i = 0; i < 4; i++)
#pragma unroll
    for (int j = 0; j < 2; j++)
#pragma unroll
      for (int r = 0; r < 4; r++) {
        int mloc = mb * 128 + wm + i * 16 + fq * 4 + r;
        int col = nb * 128 + wn + j * 16 + fr;
        if (col >= H_DIM) continue;
        float v = acc[i][j][r];
        if (mode == 0) {
          out[(size_t)mloc * H_DIM + col] = v;
        } else {
          int g = row_lo + mloc;
          int tok = etok[g];
          if (tok >= 0) out[(size_t)tok * H_DIM + col] += ew[g] * v;
        }
      }
}

// ================= fused launchers (512 threads) =============================

// blocks [0,ns): scatter ; [ns, ns+ng): shared gateup
__global__ __launch_bounds__(512, 2) void fuse_sg_k(
    int ns, int ng,
    const int* __restrict__ tki, const float* __restrict__ tkw,
    const int* __restrict__ offs16, int* __restrict__ cursor,
    int* __restrict__ etok, float* __restrict__ ew,
    const unsigned short* __restrict__ xb, const unsigned short* __restrict__ wg,
    const unsigned short* __restrict__ wu, unsigned short* __restrict__ h,
    const int* __restrict__ pcnt16, const int* __restrict__ pinfo) {
  __shared__ unsigned short lds[3 * 4096];
  int b = blockIdx.x;
  if (b < ns)
    scatter_body(b, tki, tkw, offs16, cursor, etok, ew, (int*)lds);
  else if (b < ns + ng)
    gu_body(b - ns, 1, 0, xb, wg, wu, h, etok, offs16, pcnt16, pinfo,
            lds, lds + 4096, lds + 8192);
}

// blocks [0,nd): down(dmode,dp) ; [nd, nd+ng): gateup(gshared=0, gp)
__global__ __launch_bounds__(512, 2) void fuse_dg_k(
    int nd, int dmode, int dp, int ng, int gp,
    const unsigned short* __restrict__ hbuf_d, const unsigned short* __restrict__ wd,
    float* __restrict__ out,
    const unsigned short* __restrict__ xb, const unsigned short* __restrict__ wg,
    const unsigned short* __restrict__ wu, unsigned short* __restrict__ h_g,
    const int* __restrict__ etok, const float* __restrict__ ew,
    const int* __restrict__ offs16, const int* __restrict__ pcnt16,
    const int* __restrict__ pinfo) {
  __shared__ unsigned short lds[3 * 4096];
  int b = blockIdx.x;
  if (b < nd)
    down_body(b, dmode, dp, hbuf_d, wd, out, etok, ew, offs16, pcnt16, pinfo,
              lds, lds + 4096);
  else if (b < nd + ng)
    gu_body(b - nd, 0, gp, xb, wg, wu, h_g, etok, offs16, pcnt16, pinfo,
            lds, lds + 4096, lds + 8192);
}

// ================= host =======================================================

extern "C" void kernel_launch(void* const* d_in, const int* in_sizes, int n_in,
                              void* d_out, int out_size, void* d_ws, size_t ws_size,
                              hipStream_t stream) {
  const float* x = (const float*)d_in[0];
  const float* sgw = (const float*)d_in[1];
  const float* suw = (const float*)d_in[2];
  const float* sdw = (const float*)d_in[3];
  const float* rgw = (const float*)d_in[4];
  const float* ruw = (const float*)d_in[5];
  const float* rdw = (const float*)d_in[6];
  const float* rw = (const float*)d_in[7];
  const float* rb = (const float*)d_in[8];
  float* out = (float*)d_out;
  char* ws = (char*)d_ws;

  const size_t o_xb = 0;                        // 37,748,736
  const size_t o_w = 37748736;                  // bf16 weights, 15,925,248 total
  const size_t w_sg = o_w;
  const size_t w_su = o_w + 589824;
  const size_t w_sd = o_w + 1179648;
  const size_t w_rg = o_w + 1769472;
  const size_t w_ru = o_w + 6488064;
  const size_t w_rd = o_w + 11206656;
  const size_t o_tki = o_w + 15925248;          // 53,673,984
  const size_t o_tkw = o_tki + 262144;
  const size_t o_meta = o_tkw + 262144;         // 8 KB
  const size_t o_etok = o_meta + 8192;
  const size_t o_ew = o_etok + 270336;
  const size_t o_hA = o_ew + 270336;            // 34,603,008 (33792 rows)
  const size_t o_hB = o_hA + 34603008;          // fast path only
  const size_t need_fast = o_hB + 34603008;     // 123,953,152

  unsigned short* xb = (unsigned short*)(ws + o_xb);
  int* tki = (int*)(ws + o_tki);
  float* tkw = (float*)(ws + o_tkw);
  int* counts = (int*)(ws + o_meta);
  int* cursor = counts + 512;
  int* offs16 = counts + 1024;
  int* pcnt16 = counts + 1040;
  int* pinfo = counts + 1056;
  int* etok = (int*)(ws + o_etok);
  float* ew = (float*)(ws + o_ew);
  unsigned short* hA = (unsigned short*)(ws + o_hA);
  bool fast = ws_size >= need_fast;
  unsigned short* hB = fast ? (unsigned short*)(ws + o_hB) : hA;

  unsigned short* wsg = (unsigned short*)(ws + w_sg);
  unsigned short* wsu = (unsigned short*)(ws + w_su);
  unsigned short* wsd = (unsigned short*)(ws + w_sd);
  unsigned short* wrg = (unsigned short*)(ws + w_rg);
  unsigned short* wru = (unsigned short*)(ws + w_ru);
  unsigned short* wrd = (unsigned short*)(ws + w_rd);

  hipMemsetAsync(ws + o_meta, 0, 8192, stream);
  hipMemsetAsync(etok, 0xFF, 270336, stream);
  hipMemsetAsync(ew, 0, 270336, stream);

  // K1: all conversions + router in one packed launch
  prep_k<<<NB_CVTX + NB_WHI + NB_WIH + NB_RT, 256, 0, stream>>>(
      x, xb, sgw, suw, rgw, ruw, wsg, wsu, wrg, wru, sdw, rdw, wsd, wrd,
      rw, rb, tki, tkw, counts);
  offsets_k<<<1, 64, 0, stream>>>(counts, offs16, pcnt16, pinfo);
  // K3: scatter || shared gateup -> hA
  fuse_sg_k<<<NB_SC + NB_SGU, 512, 0, stream>>>(
      NB_SC, NB_SGU, tki, tkw, offs16, cursor, etok, ew,
      xb, wsg, wsu, hA, pcnt16, pinfo);

  if (fast) {
    // K4: shared down (hA -> out, store) || p0 gateup -> hB
    fuse_dg_k<<<NB_SDN + NB_PGU, 512, 0, stream>>>(
        NB_SDN, 0, 0, NB_PGU, 0, hA, wsd, out,
        xb, wrg, wru, hB, etok, ew, offs16, pcnt16, pinfo);
    // K5: p0 down (hB -> out, RMW) || p1 gateup -> hA
    fuse_dg_k<<<NB_PDN + NB_PGU, 512, 0, stream>>>(
        NB_PDN, 1, 0, NB_PGU, 1, hB, wrd, out,
        xb, wrg, wru, hA, etok, ew, offs16, pcnt16, pinfo);
    // K6: p1 down (hA -> out, RMW)
    fuse_dg_k<<<NB_PDN, 512, 0, stream>>>(
        NB_PDN, 1, 1, 0, 0, hA, wrd, out,
        xb, wrg, wru, hA, etok, ew, offs16, pcnt16, pinfo);
  } else {
    // sequential fallback (single h buffer), same bodies
    fuse_dg_k<<<NB_SDN, 512, 0, stream>>>(
        NB_SDN, 0, 0, 0, 0, hA, wsd, out,
        xb, wrg, wru, hA, etok, ew, offs16, pcnt16, pinfo);
    fuse_dg_k<<<NB_PGU, 512, 0, stream>>>(
        0, 0, 0, NB_PGU, 0, hA, wrd, out,
        xb, wrg, wru, hA, etok, ew, offs16, pcnt16, pinfo);
    fuse_dg_k<<<NB_PDN, 512, 0, stream>>>(
        NB_PDN, 1, 0, 0, 0, hA, wrd, out,
        xb, wrg, wru, hA, etok, ew, offs16, pcnt16, pinfo);
    fuse_dg_k<<<NB_PGU, 512, 0, stream>>>(
        0, 0, 0, NB_PGU, 1, hA, wrd, out,
        xb, wrg, wru, hA, etok, ew, offs16, pcnt16, pinfo);
    fuse_dg_k<<<NB_PDN, 512, 0, stream>>>(
        NB_PDN, 1, 1, 0, 0, hA, wrd, out,
        xb, wrg, wru, hA, etok, ew, offs16, pcnt16, pinfo);
  }
}

// Round 5
// 480.643 us; speedup vs baseline: 1.4888x; 1.4888x over previous
//
#include <hip/hip_runtime.h>
#include <stdint.h>

#define T_TOK 32768
#define H_DIM 576
#define I_DIM 512
#define NEXP 8
#define WELEM 294912  // 576*512 elements per expert weight matrix
#define MAXMB 264     // per-phase max 128-row blocks

// prep_k block ranges
#define NB_CVTX 4608
#define NB_WHI 5184
#define NB_WIH 2592
#define NB_RT 1024

typedef __attribute__((ext_vector_type(8))) short short8;
typedef __attribute__((ext_vector_type(4))) float f32x4;
typedef __attribute__((ext_vector_type(4))) float f4;
typedef __attribute__((ext_vector_type(4))) unsigned short u16x4;

__device__ __forceinline__ unsigned short f2bf(float f) {
  union { float f; unsigned u; } v; v.f = f;
  unsigned r = (v.u + 0x7fffu + ((v.u >> 16) & 1u)) >> 16;
  return (unsigned short)r;
}

__device__ __forceinline__ void gl16(const void* g, void* l) {
  __builtin_amdgcn_global_load_lds(
      (const __attribute__((address_space(1))) unsigned*)g,
      (__attribute__((address_space(3))) unsigned*)l, 16, 0, 0);
}

// ================= prep: cvt_x || cvt_w(HI) || cvt_w(IH) || router ===========
// Simple bodies only — NO MFMA kernels fused here (round-4 lesson: union
// register allocation wrecked the GEMM codegen).

__global__ __launch_bounds__(256) void prep_k(
    const float* __restrict__ x, unsigned short* __restrict__ xb,
    const float* __restrict__ sgw, const float* __restrict__ suw,
    const float* __restrict__ rgw, const float* __restrict__ ruw,
    unsigned short* __restrict__ wsg, unsigned short* __restrict__ wsu,
    unsigned short* __restrict__ wrg, unsigned short* __restrict__ wru,
    const float* __restrict__ sdw, const float* __restrict__ rdw,
    unsigned short* __restrict__ wsd, unsigned short* __restrict__ wrd,
    const float* __restrict__ rw, const float* __restrict__ rb,
    int* __restrict__ tki, float* __restrict__ tkw, int* __restrict__ counts) {
  __shared__ float tile[32][33];
  __shared__ int hist[16];
  int b = blockIdx.x, tid = threadIdx.x;
  if (b < NB_CVTX) {
    size_t base = (size_t)b * 256 + tid;
#pragma unroll
    for (int it = 0; it < 4; it++) {
      size_t i = (base + (size_t)it * NB_CVTX * 256) * 4;
      f4 v = *(const f4*)(x + i);
      u16x4 o;
      o.x = f2bf(v.x); o.y = f2bf(v.y); o.z = f2bf(v.z); o.w = f2bf(v.w);
      *(u16x4*)(xb + i) = o;
    }
  } else if (b < NB_CVTX + NB_WHI) {
    // [576][512] -> [512][576] bf16; z0=sgw z1=suw z2-9=rgw z10-17=ruw
    int b2 = b - NB_CVTX;
    int z = b2 / 288, r = b2 % 288, bx = r & 15, by = r >> 4;
    int tx = tid & 31, ty = tid >> 5;
    const float* src; unsigned short* dst;
    if (z == 0)      { src = sgw;                            dst = wsg; }
    else if (z == 1) { src = suw;                            dst = wsu; }
    else if (z < 10) { src = rgw + (size_t)(z - 2) * WELEM;  dst = wrg + (size_t)(z - 2) * WELEM; }
    else             { src = ruw + (size_t)(z - 10) * WELEM; dst = wru + (size_t)(z - 10) * WELEM; }
    int r0 = by * 32, c0 = bx * 32;
    for (int i = ty; i < 32; i += 8)
      tile[i][tx] = src[(size_t)(r0 + i) * 512 + c0 + tx];
    __syncthreads();
    for (int i = ty; i < 32; i += 8)
      dst[(size_t)(c0 + i) * 576 + r0 + tx] = f2bf(tile[tx][i]);
  } else if (b < NB_CVTX + NB_WHI + NB_WIH) {
    // [512][576] -> [576][512] bf16; z0=sdw z1-8=rdw
    int b3 = b - NB_CVTX - NB_WHI;
    int z = b3 / 288, r = b3 % 288, bx = r % 18, by = r / 18;
    int tx = tid & 31, ty = tid >> 5;
    const float* src = (z == 0) ? sdw : rdw + (size_t)(z - 1) * WELEM;
    unsigned short* dst = (z == 0) ? wsd : wrd + (size_t)(z - 1) * WELEM;
    int r0 = by * 32, c0 = bx * 32;
    for (int i = ty; i < 32; i += 8)
      tile[i][tx] = src[(size_t)(r0 + i) * 576 + c0 + tx];
    __syncthreads();
    for (int i = ty; i < 32; i += 8)
      dst[(size_t)(c0 + i) * 512 + r0 + tx] = f2bf(tile[tx][i]);
  } else {
    // router: 8 lanes/token, 72-elem coalesced H-slices, exact fp32 logits
    int rblk = b - NB_CVTX - NB_WHI - NB_WIH;
    int wv = tid >> 6, lane = tid & 63, tk = lane >> 3, sl = lane & 7;
    int t = rblk * 32 + wv * 8 + tk;
    if (tid < 16) hist[tid] = 0;
    const float* xr = x + (size_t)t * H_DIM + sl * 72;
    const float* rwp = rw + sl * 72 * NEXP;
    float acc[NEXP];
#pragma unroll
    for (int e = 0; e < NEXP; e++) acc[e] = 0.f;
    for (int hh = 0; hh < 72; hh += 4) {
      f4 xv = *(const f4*)(xr + hh);
#pragma unroll
      for (int j = 0; j < 4; j++) {
        f4 w0 = *(const f4*)(rwp + (hh + j) * 8);
        f4 w1 = *(const f4*)(rwp + (hh + j) * 8 + 4);
        float xs = xv[j];
        acc[0] += xs * w0.x; acc[1] += xs * w0.y;
        acc[2] += xs * w0.z; acc[3] += xs * w0.w;
        acc[4] += xs * w1.x; acc[5] += xs * w1.y;
        acc[6] += xs * w1.z; acc[7] += xs * w1.w;
      }
    }
#pragma unroll
    for (int off = 1; off < 8; off <<= 1)
#pragma unroll
      for (int e = 0; e < NEXP; e++) acc[e] += __shfl_xor(acc[e], off);
    __syncthreads();
    if (sl == 0) {
      float l[NEXP];
#pragma unroll
      for (int e = 0; e < NEXP; e++) l[e] = acc[e] + rb[e];
      int e0 = 0;
#pragma unroll
      for (int e = 1; e < NEXP; e++) if (l[e] > l[e0]) e0 = e;
      int e1 = -1;
#pragma unroll
      for (int e = 0; e < NEXP; e++) {
        if (e == e0) continue;
        if (e1 < 0 || l[e] > l[e1]) e1 = e;
      }
      float w0 = 1.f / (1.f + __expf(l[e1] - l[e0]));
      tki[t * 2] = e0; tki[t * 2 + 1] = e1;
      tkw[t * 2] = w0; tkw[t * 2 + 1] = 1.f - w0;
      atomicAdd(&hist[e0], 1);
      atomicAdd(&hist[8 + e1], 1);
    }
    __syncthreads();
    if (tid < 16) atomicAdd(&counts[tid * 32], hist[tid]);
  }
}

__global__ void offsets_k(const int* __restrict__ counts, int* __restrict__ offs16,
                          int* __restrict__ pcnt16, int* __restrict__ pinfo) {
  if (threadIdx.x == 0) {
    int o = 0;
    for (int s = 0; s < 16; s++) {
      int c = counts[s * 32];
      int pc = (c + 127) & ~127;
      offs16[s] = o; pcnt16[s] = pc;
      o += pc;
    }
    pinfo[0] = offs16[8];
    pinfo[1] = o - offs16[8];
  }
}

__global__ __launch_bounds__(256) void scatter_k(
    const int* __restrict__ tki, const float* __restrict__ tkw,
    const int* __restrict__ offs16, int* __restrict__ cursor /*stride 32*/,
    int* __restrict__ etok, float* __restrict__ ew) {
  __shared__ int hist[16], base[16], lcur[16];
  int tid = threadIdx.x;
  if (tid < 16) { hist[tid] = 0; lcur[tid] = 0; }
  __syncthreads();
  int t = blockIdx.x * 256 + tid;
  int s0 = tki[t * 2], s1 = 8 + tki[t * 2 + 1];
  atomicAdd(&hist[s0], 1);
  atomicAdd(&hist[s1], 1);
  __syncthreads();
  if (tid < 16) base[tid] = atomicAdd(&cursor[tid * 32], hist[tid]);
  __syncthreads();
#pragma unroll
  for (int k = 0; k < 2; k++) {
    int s = (k == 0) ? s0 : s1;
    int r = atomicAdd(&lcur[s], 1);
    int slot = offs16[s] + base[s] + r;
    etok[slot] = t;
    ew[slot] = tkw[t * 2 + k];
  }
}

// ---------------- fused gate/up GEMM + silu (unchanged from r3) --------------
template <int SHARED>
__global__ __launch_bounds__(512, 2) void gateup_k(
    const unsigned short* __restrict__ xb, const unsigned short* __restrict__ wg,
    const unsigned short* __restrict__ wu, unsigned short* __restrict__ h,
    const int* __restrict__ etok, const int* __restrict__ offs16,
    const int* __restrict__ pcnt16, const int* __restrict__ pinfo, int p) {
  int mb = blockIdx.x;
  int nrows = SHARED ? T_TOK : pinfo[p];
  if (mb * 128 >= nrows) return;
  int row_lo = (SHARED || p == 0) ? 0 : pinfo[0];
  int nb = blockIdx.y;
  __shared__ unsigned short As[128 * 32];
  __shared__ unsigned short Bg[128 * 32];
  __shared__ unsigned short Bu[128 * 32];
  int t = threadIdx.x;
  int wv = t >> 6, lane = t & 63;
  int ar = t >> 2, seg = t & 3;
  int sg = seg ^ ((ar >> 1) & 3);
  int m0 = mb * 128 + ar;
  int tok0, e = 0;
  if (SHARED) {
    tok0 = m0;
  } else {
    int g = row_lo + m0;
    int s = 0;
#pragma unroll
    for (int i = 0; i < 15; i++) s += (g >= offs16[i] + pcnt16[i]) ? 1 : 0;
    e = s & 7;
    tok0 = etok[g];
    if (tok0 < 0) tok0 = 0;
  }
  const unsigned short* ga = xb + (size_t)tok0 * H_DIM + sg * 8;
  int n0 = nb * 128 + ar;
  const unsigned short* gg = wg + (size_t)e * WELEM + (size_t)n0 * H_DIM + sg * 8;
  const unsigned short* gu = wu + (size_t)e * WELEM + (size_t)n0 * H_DIM + sg * 8;
  char* lA = (char*)As + wv * 1024;
  char* lG = (char*)Bg + wv * 1024;
  char* lU = (char*)Bu + wv * 1024;
  int fr = lane & 15, fq = lane >> 4;
  int wm = (wv >> 2) * 64, wn = (wv & 3) * 32;
  f32x4 accg[4][2] = {};
  f32x4 accu[4][2] = {};
  for (int k0 = 0; k0 < H_DIM; k0 += 32) {
    gl16(ga + k0, lA);
    gl16(gg + k0, lG);
    gl16(gu + k0, lU);
    __syncthreads();
    short8 a[4], g[2], u[2];
#pragma unroll
    for (int i = 0; i < 4; i++) {
      int r = wm + i * 16 + fr;
      a[i] = *(const short8*)&As[r * 32 + (fq ^ ((r >> 1) & 3)) * 8];
    }
#pragma unroll
    for (int j = 0; j < 2; j++) {
      int r = wn + j * 16 + fr;
      int sw = (fq ^ ((r >> 1) & 3)) * 8;
      g[j] = *(const short8*)&Bg[r * 32 + sw];
      u[j] = *(const short8*)&Bu[r * 32 + sw];
    }
#pragma unroll
    for (int i = 0; i < 4; i++)
#pragma unroll
      for (int j = 0; j < 2; j++) {
        accg[i][j] = __builtin_amdgcn_mfma_f32_16x16x32_bf16(a[i], g[j], accg[i][j], 0, 0, 0);
        accu[i][j] = __builtin_amdgcn_mfma_f32_16x16x32_bf16(a[i], u[j], accu[i][j], 0, 0, 0);
      }
    __syncthreads();
  }
#pragma unroll
  for (int i = 0; i < 4; i++)
#pragma unroll
    for (int j = 0; j < 2; j++)
#pragma unroll
      for (int r = 0; r < 4; r++) {
        int row = mb * 128 + wm + i * 16 + fq * 4 + r;
        int col = nb * 128 + wn + j * 16 + fr;
        float gv = accg[i][j][r], uv = accu[i][j][r];
        float hv = (gv / (1.f + __expf(-gv))) * uv;
        h[(size_t)row * I_DIM + col] = f2bf(hv);
      }
}

// ---------------- down GEMM with LDS-staged coalesced epilogue ---------------
// MODE 0: shared expert, direct store. MODE 1: phase-p non-atomic scatter RMW.
// Epilogue stages 32-row chunks of the fp32 acc tile in LDS (reusing As/Bs,
// 16 KB), then writes float4 in 512B-contiguous runs (half-wave per row).
template <int MODE>
__global__ __launch_bounds__(512, 2) void down_k(
    const unsigned short* __restrict__ hbuf, const unsigned short* __restrict__ wd,
    float* __restrict__ out, const int* __restrict__ etok, const float* __restrict__ ew,
    const int* __restrict__ offs16, const int* __restrict__ pcnt16,
    const int* __restrict__ pinfo, int p) {
  int mb = blockIdx.x;
  int nrows = (MODE == 0) ? T_TOK : pinfo[p];
  if (mb * 128 >= nrows) return;
  int row_lo = (MODE == 0 || p == 0) ? 0 : pinfo[0];
  int nb = blockIdx.y;
  __shared__ unsigned short AB[2][128 * 32];  // A | B ; reused as fp32 staging
  int t = threadIdx.x;
  int wv = t >> 6, lane = t & 63;
  int ar = t >> 2, seg = t & 3;
  int sg = seg ^ ((ar >> 1) & 3);
  int e = 0;
  if (MODE == 1) {
    int g = row_lo + mb * 128 + ar;
    int s = 0;
#pragma unroll
    for (int i = 0; i < 15; i++) s += (g >= offs16[i] + pcnt16[i]) ? 1 : 0;
    e = s & 7;
  }
  const unsigned short* ga = hbuf + (size_t)(mb * 128 + ar) * I_DIM + sg * 8;
  int n0 = nb * 128 + ar;
  if (n0 > H_DIM - 1) n0 = H_DIM - 1;
  const unsigned short* gb = wd + (size_t)e * WELEM + (size_t)n0 * I_DIM + sg * 8;
  char* lA = (char*)AB[0] + wv * 1024;
  char* lB = (char*)AB[1] + wv * 1024;
  int fr = lane & 15, fq = lane >> 4;
  int wm = (wv >> 2) * 64, wn = (wv & 3) * 32;
  f32x4 acc[4][2] = {};
  for (int k0 = 0; k0 < I_DIM; k0 += 32) {
    gl16(ga + k0, lA);
    gl16(gb + k0, lB);
    __syncthreads();
    short8 a[4], b2[2];
#pragma unroll
    for (int i = 0; i < 4; i++) {
      int r = wm + i * 16 + fr;
      a[i] = *(const short8*)&AB[0][r * 32 + (fq ^ ((r >> 1) & 3)) * 8];
    }
#pragma unroll
    for (int j = 0; j < 2; j++) {
      int r = wn + j * 16 + fr;
      b2[j] = *(const short8*)&AB[1][r * 32 + (fq ^ ((r >> 1) & 3)) * 8];
    }
#pragma unroll
    for (int i = 0; i < 4; i++)
#pragma unroll
      for (int j = 0; j < 2; j++)
        acc[i][j] = __builtin_amdgcn_mfma_f32_16x16x32_bf16(a[i], b2[j], acc[i][j], 0, 0, 0);
    __syncthreads();
  }
  // ---- staged epilogue: 4 chunks of 32 rows x 128 cols fp32 (16 KB) ----
  float* st = (float*)AB;
  int q = t & 31;
  int colv = nb * 128 + q * 4;
  bool colok = colv < H_DIM;
#pragma unroll
  for (int c = 0; c < 4; c++) {
    __syncthreads();
    if ((wm == 64) == (c >= 2)) {
#pragma unroll
      for (int ii = 0; ii < 2; ii++) {
        int i = (c & 1) * 2 + ii;
#pragma unroll
        for (int j = 0; j < 2; j++)
#pragma unroll
          for (int r = 0; r < 4; r++)
            st[(ii * 16 + fq * 4 + r) * 128 + wn + j * 16 + fr] = acc[i][j][r];
      }
    }
    __syncthreads();
#pragma unroll
    for (int ps = 0; ps < 2; ps++) {
      int lr = (t >> 5) + ps * 16;
      int mloc = mb * 128 + c * 32 + lr;
      if (colok) {
        f4 v = *(f4*)&st[lr * 128 + q * 4];
        if (MODE == 0) {
          *(f4*)&out[(size_t)mloc * H_DIM + colv] = v;
        } else {
          int g = row_lo + mloc;
          int tok = etok[g];
          if (tok >= 0) {
            float w = ew[g];
            float* op = &out[(size_t)tok * H_DIM + colv];
            f4 o = *(f4*)op;
            o.x += w * v.x; o.y += w * v.y; o.z += w * v.z; o.w += w * v.w;
            *(f4*)op = o;
          }
        }
      }
    }
  }
}

// ================= host =======================================================

extern "C" void kernel_launch(void* const* d_in, const int* in_sizes, int n_in,
                              void* d_out, int out_size, void* d_ws, size_t ws_size,
                              hipStream_t stream) {
  const float* x = (const float*)d_in[0];
  const float* sgw = (const float*)d_in[1];
  const float* suw = (const float*)d_in[2];
  const float* sdw = (const float*)d_in[3];
  const float* rgw = (const float*)d_in[4];
  const float* ruw = (const float*)d_in[5];
  const float* rdw = (const float*)d_in[6];
  const float* rw = (const float*)d_in[7];
  const float* rb = (const float*)d_in[8];
  float* out = (float*)d_out;
  char* ws = (char*)d_ws;

  const size_t o_xb = 0;                        // 37,748,736
  const size_t o_w = 37748736;
  const size_t w_sg = o_w;
  const size_t w_su = o_w + 589824;
  const size_t w_sd = o_w + 1179648;
  const size_t w_rg = o_w + 1769472;
  const size_t w_ru = o_w + 6488064;
  const size_t w_rd = o_w + 11206656;
  const size_t o_tki = o_w + 15925248;
  const size_t o_tkw = o_tki + 262144;
  const size_t o_meta = o_tkw + 262144;
  const size_t o_etok = o_meta + 8192;
  const size_t o_ew = o_etok + 270336;
  const size_t o_h = o_ew + 270336;             // 34,603,008
  // total 89,350,144 B

  unsigned short* xb = (unsigned short*)(ws + o_xb);
  int* tki = (int*)(ws + o_tki);
  float* tkw = (float*)(ws + o_tkw);
  int* counts = (int*)(ws + o_meta);
  int* cursor = counts + 512;
  int* offs16 = counts + 1024;
  int* pcnt16 = counts + 1040;
  int* pinfo = counts + 1056;
  int* etok = (int*)(ws + o_etok);
  float* ew = (float*)(ws + o_ew);
  unsigned short* h = (unsigned short*)(ws + o_h);

  unsigned short* wsg = (unsigned short*)(ws + w_sg);
  unsigned short* wsu = (unsigned short*)(ws + w_su);
  unsigned short* wsd = (unsigned short*)(ws + w_sd);
  unsigned short* wrg = (unsigned short*)(ws + w_rg);
  unsigned short* wru = (unsigned short*)(ws + w_ru);
  unsigned short* wrd = (unsigned short*)(ws + w_rd);

  hipMemsetAsync(ws + o_meta, 0, 8192, stream);
  hipMemsetAsync(etok, 0xFF, 270336, stream);
  hipMemsetAsync(ew, 0, 270336, stream);

  prep_k<<<NB_CVTX + NB_WHI + NB_WIH + NB_RT, 256, 0, stream>>>(
      x, xb, sgw, suw, rgw, ruw, wsg, wsu, wrg, wru, sdw, rdw, wsd, wrd,
      rw, rb, tki, tkw, counts);
  offsets_k<<<1, 64, 0, stream>>>(counts, offs16, pcnt16, pinfo);
  scatter_k<<<128, 256, 0, stream>>>(tki, tkw, offs16, cursor, etok, ew);

  // shared expert
  gateup_k<1><<<dim3(256, 4), 512, 0, stream>>>(
      xb, wsg, wsu, h, nullptr, nullptr, nullptr, nullptr, 0);
  down_k<0><<<dim3(256, 5), 512, 0, stream>>>(
      h, wsd, out, nullptr, nullptr, nullptr, nullptr, nullptr, 0);

  // routed experts: one gate/up + one down per k-phase (race-free RMW)
  for (int p = 0; p < 2; p++) {
    gateup_k<0><<<dim3(MAXMB, 4), 512, 0, stream>>>(
        xb, wrg, wru, h, etok, offs16, pcnt16, pinfo, p);
    down_k<1><<<dim3(MAXMB, 5), 512, 0, stream>>>(
        h, wrd, out, etok, ew, offs16, pcnt16, pinfo, p);
  }
}

// Round 6
// 378.092 us; speedup vs baseline: 1.8926x; 1.2712x over previous
//
#include <hip/hip_runtime.h>
#include <stdint.h>

#define T_TOK 32768
#define H_DIM 576
#define I_DIM 512
#define NEXP 8
#define WELEM 294912  // 576*512 elements per expert weight matrix
#define MAXMB 264     // per-phase max 128-row blocks

typedef __attribute__((ext_vector_type(8))) short short8;
typedef __attribute__((ext_vector_type(4))) float f32x4;
typedef __attribute__((ext_vector_type(4))) float f4;
typedef __attribute__((ext_vector_type(4))) unsigned short u16x4;

__device__ __forceinline__ unsigned short f2bf(float f) {
  union { float f; unsigned u; } v; v.f = f;
  unsigned r = (v.u + 0x7fffu + ((v.u >> 16) & 1u)) >> 16;
  return (unsigned short)r;
}

__device__ __forceinline__ void gl16(const void* g, void* l) {
  __builtin_amdgcn_global_load_lds(
      (const __attribute__((address_space(1))) unsigned*)g,
      (__attribute__((address_space(3))) unsigned*)l, 16, 0, 0);
}

// ============ fused router + x->bf16 convert (coalesced, 1 read of x) ========
// 256 blocks x 256 threads; block owns 128 tokens. 18 chunks of 32 h-rows
// ([0,288) for thread-half 0, [288,576) for half 1). Loads are f4 with lanes
// 0-3 covering one row's 64B => fully-consumed lines. xb written in-register.
__global__ __launch_bounds__(256) void routercvt_k(
    const float* __restrict__ x, unsigned short* __restrict__ xb,
    const float* __restrict__ rw, const float* __restrict__ rb,
    int* __restrict__ tki, float* __restrict__ tkw, int* __restrict__ counts) {
  __shared__ float lrw[H_DIM * NEXP];   // 18.4 KB
  __shared__ float tile[32][132];       // 16.9 KB, pad 132 (bank-safe)
  __shared__ float red[128][8];         // 4 KB
  __shared__ int hist[16];
  int tid = threadIdx.x;
  for (int i = tid; i < 1152; i += 256)
    *(f4*)&lrw[i * 4] = *(const f4*)&rw[i * 4];
  if (tid < 16) hist[tid] = 0;
  int t0 = blockIdx.x * 128;
  int half = tid >> 7, tl = tid & 127;
  float acc[NEXP] = {};
  for (int c = 0; c < 18; c++) {
    __syncthreads();  // tile reuse guard (also orders lrw staging at c=0)
#pragma unroll
    for (int k = 0; k < 4; k++) {
      int f = tid + k * 256;            // 0..1023
      int rgrp = f >> 9, fl = f & 511;
      int tl2 = fl >> 2, seg = fl & 3;
      int h = (rgrp ? 288 : 0) + c * 16 + seg * 4;
      size_t gi = (size_t)(t0 + tl2) * H_DIM + h;
      f4 v = *(const f4*)(x + gi);
      u16x4 o;
      o.x = f2bf(v.x); o.y = f2bf(v.y); o.z = f2bf(v.z); o.w = f2bf(v.w);
      *(u16x4*)(xb + gi) = o;
      int row = rgrp * 16 + seg * 4;
      tile[row + 0][tl2] = v.x; tile[row + 1][tl2] = v.y;
      tile[row + 2][tl2] = v.z; tile[row + 3][tl2] = v.w;
    }
    __syncthreads();
    int hbase = half * 288 + c * 16;
    int rbase = half * 16;
#pragma unroll
    for (int hh = 0; hh < 16; hh++) {
      float xv = tile[rbase + hh][tl];
      f4 w0 = *(const f4*)&lrw[(hbase + hh) * 8];
      f4 w1 = *(const f4*)&lrw[(hbase + hh) * 8 + 4];
      acc[0] += xv * w0.x; acc[1] += xv * w0.y;
      acc[2] += xv * w0.z; acc[3] += xv * w0.w;
      acc[4] += xv * w1.x; acc[5] += xv * w1.y;
      acc[6] += xv * w1.z; acc[7] += xv * w1.w;
    }
  }
  if (half) {
#pragma unroll
    for (int e = 0; e < NEXP; e++) red[tl][e] = acc[e];
  }
  __syncthreads();
  if (!half) {
    int t = t0 + tl;
    float l[NEXP];
#pragma unroll
    for (int e = 0; e < NEXP; e++) l[e] = acc[e] + red[tl][e] + rb[e];
    int e0 = 0;
#pragma unroll
    for (int e = 1; e < NEXP; e++) if (l[e] > l[e0]) e0 = e;
    int e1 = -1;
#pragma unroll
    for (int e = 0; e < NEXP; e++) {
      if (e == e0) continue;
      if (e1 < 0 || l[e] > l[e1]) e1 = e;
    }
    float w0 = 1.f / (1.f + __expf(l[e1] - l[e0]));
    tki[t * 2] = e0; tki[t * 2 + 1] = e1;
    tkw[t * 2] = w0; tkw[t * 2 + 1] = 1.f - w0;
    atomicAdd(&hist[e0], 1);
    atomicAdd(&hist[8 + e1], 1);
  }
  __syncthreads();
  if (tid < 16) atomicAdd(&counts[tid * 32], hist[tid]);
}

// ============ weight transposes (standalone, round-3 proven) =================
// [576][512] fp32 -> [512][576] bf16; z0=sgw z1=suw z2-9=rgw z10-17=ruw
__global__ void cvt_HI_k(const float* __restrict__ sgw, const float* __restrict__ suw,
                         const float* __restrict__ rgw, const float* __restrict__ ruw,
                         unsigned short* __restrict__ wsg, unsigned short* __restrict__ wsu,
                         unsigned short* __restrict__ wrg, unsigned short* __restrict__ wru) {
  __shared__ float tile[32][33];
  int z = blockIdx.z;
  const float* src; unsigned short* dst;
  if (z == 0)      { src = sgw;                            dst = wsg; }
  else if (z == 1) { src = suw;                            dst = wsu; }
  else if (z < 10) { src = rgw + (size_t)(z - 2) * WELEM;  dst = wrg + (size_t)(z - 2) * WELEM; }
  else             { src = ruw + (size_t)(z - 10) * WELEM; dst = wru + (size_t)(z - 10) * WELEM; }
  int r0 = blockIdx.y * 32, c0 = blockIdx.x * 32;
  for (int i = threadIdx.y; i < 32; i += 8)
    tile[i][threadIdx.x] = src[(size_t)(r0 + i) * 512 + c0 + threadIdx.x];
  __syncthreads();
  for (int i = threadIdx.y; i < 32; i += 8)
    dst[(size_t)(c0 + i) * 576 + r0 + threadIdx.x] = f2bf(tile[threadIdx.x][i]);
}

// [512][576] fp32 -> [576][512] bf16; z0=sdw z1-8=rdw
__global__ void cvt_IH_k(const float* __restrict__ sdw, const float* __restrict__ rdw,
                         unsigned short* __restrict__ wsd, unsigned short* __restrict__ wrd) {
  __shared__ float tile[32][33];
  int z = blockIdx.z;
  const float* src = (z == 0) ? sdw : rdw + (size_t)(z - 1) * WELEM;
  unsigned short* dst = (z == 0) ? wsd : wrd + (size_t)(z - 1) * WELEM;
  int r0 = blockIdx.y * 32, c0 = blockIdx.x * 32;
  for (int i = threadIdx.y; i < 32; i += 8)
    tile[i][threadIdx.x] = src[(size_t)(r0 + i) * 576 + c0 + threadIdx.x];
  __syncthreads();
  for (int i = threadIdx.y; i < 32; i += 8)
    dst[(size_t)(c0 + i) * 512 + r0 + threadIdx.x] = f2bf(tile[threadIdx.x][i]);
}

__global__ void offsets_k(const int* __restrict__ counts, int* __restrict__ offs16,
                          int* __restrict__ pcnt16, int* __restrict__ pinfo) {
  if (threadIdx.x == 0) {
    int o = 0;
    for (int s = 0; s < 16; s++) {
      int c = counts[s * 32];
      int pc = (c + 127) & ~127;
      offs16[s] = o; pcnt16[s] = pc;
      o += pc;
    }
    pinfo[0] = offs16[8];
    pinfo[1] = o - offs16[8];
  }
}

__global__ __launch_bounds__(256) void scatter_k(
    const int* __restrict__ tki, const float* __restrict__ tkw,
    const int* __restrict__ offs16, int* __restrict__ cursor /*stride 32*/,
    int* __restrict__ etok, float* __restrict__ ew) {
  __shared__ int hist[16], base[16], lcur[16];
  int tid = threadIdx.x;
  if (tid < 16) { hist[tid] = 0; lcur[tid] = 0; }
  __syncthreads();
  int t = blockIdx.x * 256 + tid;
  int s0 = tki[t * 2], s1 = 8 + tki[t * 2 + 1];
  atomicAdd(&hist[s0], 1);
  atomicAdd(&hist[s1], 1);
  __syncthreads();
  if (tid < 16) base[tid] = atomicAdd(&cursor[tid * 32], hist[tid]);
  __syncthreads();
#pragma unroll
  for (int k = 0; k < 2; k++) {
    int s = (k == 0) ? s0 : s1;
    int r = atomicAdd(&lcur[s], 1);
    int slot = offs16[s] + base[s] + r;
    etok[slot] = t;
    ew[slot] = tkw[t * 2 + k];
  }
}

// ---------------- fused gate/up GEMM + silu ----------------
template <int SHARED>
__global__ __launch_bounds__(512, 2) void gateup_k(
    const unsigned short* __restrict__ xb, const unsigned short* __restrict__ wg,
    const unsigned short* __restrict__ wu, unsigned short* __restrict__ h,
    const int* __restrict__ etok, const int* __restrict__ offs16,
    const int* __restrict__ pcnt16, const int* __restrict__ pinfo, int p) {
  int mb = blockIdx.x;
  int nrows = SHARED ? T_TOK : pinfo[p];
  if (mb * 128 >= nrows) return;
  int row_lo = (SHARED || p == 0) ? 0 : pinfo[0];
  int nb = blockIdx.y;
  __shared__ unsigned short As[128 * 32];
  __shared__ unsigned short Bg[128 * 32];
  __shared__ unsigned short Bu[128 * 32];
  int t = threadIdx.x;
  int wv = t >> 6, lane = t & 63;
  int ar = t >> 2, seg = t & 3;
  int sg = seg ^ ((ar >> 1) & 3);
  int m0 = mb * 128 + ar;
  int tok0, e = 0;
  if (SHARED) {
    tok0 = m0;
  } else {
    int g = row_lo + m0;
    int s = 0;
#pragma unroll
    for (int i = 0; i < 15; i++) s += (g >= offs16[i] + pcnt16[i]) ? 1 : 0;
    e = s & 7;
    tok0 = etok[g];
    if (tok0 < 0) tok0 = 0;
  }
  const unsigned short* ga = xb + (size_t)tok0 * H_DIM + sg * 8;
  int n0 = nb * 128 + ar;
  const unsigned short* gg = wg + (size_t)e * WELEM + (size_t)n0 * H_DIM + sg * 8;
  const unsigned short* gu = wu + (size_t)e * WELEM + (size_t)n0 * H_DIM + sg * 8;
  char* lA = (char*)As + wv * 1024;
  char* lG = (char*)Bg + wv * 1024;
  char* lU = (char*)Bu + wv * 1024;
  int fr = lane & 15, fq = lane >> 4;
  int wm = (wv >> 2) * 64, wn = (wv & 3) * 32;
  f32x4 accg[4][2] = {};
  f32x4 accu[4][2] = {};
  for (int k0 = 0; k0 < H_DIM; k0 += 32) {
    gl16(ga + k0, lA);
    gl16(gg + k0, lG);
    gl16(gu + k0, lU);
    __syncthreads();
    short8 a[4], g[2], u[2];
#pragma unroll
    for (int i = 0; i < 4; i++) {
      int r = wm + i * 16 + fr;
      a[i] = *(const short8*)&As[r * 32 + (fq ^ ((r >> 1) & 3)) * 8];
    }
#pragma unroll
    for (int j = 0; j < 2; j++) {
      int r = wn + j * 16 + fr;
      int sw = (fq ^ ((r >> 1) & 3)) * 8;
      g[j] = *(const short8*)&Bg[r * 32 + sw];
      u[j] = *(const short8*)&Bu[r * 32 + sw];
    }
#pragma unroll
    for (int i = 0; i < 4; i++)
#pragma unroll
      for (int j = 0; j < 2; j++) {
        accg[i][j] = __builtin_amdgcn_mfma_f32_16x16x32_bf16(a[i], g[j], accg[i][j], 0, 0, 0);
        accu[i][j] = __builtin_amdgcn_mfma_f32_16x16x32_bf16(a[i], u[j], accu[i][j], 0, 0, 0);
      }
    __syncthreads();
  }
#pragma unroll
  for (int i = 0; i < 4; i++)
#pragma unroll
    for (int j = 0; j < 2; j++)
#pragma unroll
      for (int r = 0; r < 4; r++) {
        int row = mb * 128 + wm + i * 16 + fq * 4 + r;
        int col = nb * 128 + wn + j * 16 + fr;
        float gv = accg[i][j][r], uv = accu[i][j][r];
        float hv = (gv / (1.f + __expf(-gv))) * uv;
        h[(size_t)row * I_DIM + col] = f2bf(hv);
      }
}

// ---------------- down GEMM with LDS-staged coalesced epilogue ---------------
template <int MODE>
__global__ __launch_bounds__(512, 2) void down_k(
    const unsigned short* __restrict__ hbuf, const unsigned short* __restrict__ wd,
    float* __restrict__ out, const int* __restrict__ etok, const float* __restrict__ ew,
    const int* __restrict__ offs16, const int* __restrict__ pcnt16,
    const int* __restrict__ pinfo, int p) {
  int mb = blockIdx.x;
  int nrows = (MODE == 0) ? T_TOK : pinfo[p];
  if (mb * 128 >= nrows) return;
  int row_lo = (MODE == 0 || p == 0) ? 0 : pinfo[0];
  int nb = blockIdx.y;
  __shared__ unsigned short AB[2][128 * 32];
  int t = threadIdx.x;
  int wv = t >> 6, lane = t & 63;
  int ar = t >> 2, seg = t & 3;
  int sg = seg ^ ((ar >> 1) & 3);
  int e = 0;
  if (MODE == 1) {
    int g = row_lo + mb * 128 + ar;
    int s = 0;
#pragma unroll
    for (int i = 0; i < 15; i++) s += (g >= offs16[i] + pcnt16[i]) ? 1 : 0;
    e = s & 7;
  }
  const unsigned short* ga = hbuf + (size_t)(mb * 128 + ar) * I_DIM + sg * 8;
  int n0 = nb * 128 + ar;
  if (n0 > H_DIM - 1) n0 = H_DIM - 1;
  const unsigned short* gb = wd + (size_t)e * WELEM + (size_t)n0 * I_DIM + sg * 8;
  char* lA = (char*)AB[0] + wv * 1024;
  char* lB = (char*)AB[1] + wv * 1024;
  int fr = lane & 15, fq = lane >> 4;
  int wm = (wv >> 2) * 64, wn = (wv & 3) * 32;
  f32x4 acc[4][2] = {};
  for (int k0 = 0; k0 < I_DIM; k0 += 32) {
    gl16(ga + k0, lA);
    gl16(gb + k0, lB);
    __syncthreads();
    short8 a[4], b2[2];
#pragma unroll
    for (int i = 0; i < 4; i++) {
      int r = wm + i * 16 + fr;
      a[i] = *(const short8*)&AB[0][r * 32 + (fq ^ ((r >> 1) & 3)) * 8];
    }
#pragma unroll
    for (int j = 0; j < 2; j++) {
      int r = wn + j * 16 + fr;
      b2[j] = *(const short8*)&AB[1][r * 32 + (fq ^ ((r >> 1) & 3)) * 8];
    }
#pragma unroll
    for (int i = 0; i < 4; i++)
#pragma unroll
      for (int j = 0; j < 2; j++)
        acc[i][j] = __builtin_amdgcn_mfma_f32_16x16x32_bf16(a[i], b2[j], acc[i][j], 0, 0, 0);
    __syncthreads();
  }
  // staged epilogue: 4 chunks of 32 rows x 128 cols fp32 (16 KB LDS reuse)
  float* st = (float*)AB;
  int q = t & 31;
  int colv = nb * 128 + q * 4;
  bool colok = colv < H_DIM;
#pragma unroll
  for (int c = 0; c < 4; c++) {
    __syncthreads();
    if ((wm == 64) == (c >= 2)) {
#pragma unroll
      for (int ii = 0; ii < 2; ii++) {
        int i = (c & 1) * 2 + ii;
#pragma unroll
        for (int j = 0; j < 2; j++)
#pragma unroll
          for (int r = 0; r < 4; r++)
            st[(ii * 16 + fq * 4 + r) * 128 + wn + j * 16 + fr] = acc[i][j][r];
      }
    }
    __syncthreads();
#pragma unroll
    for (int ps = 0; ps < 2; ps++) {
      int lr = (t >> 5) + ps * 16;
      int mloc = mb * 128 + c * 32 + lr;
      if (colok) {
        f4 v = *(f4*)&st[lr * 128 + q * 4];
        if (MODE == 0) {
          *(f4*)&out[(size_t)mloc * H_DIM + colv] = v;
        } else {
          int g = row_lo + mloc;
          int tok = etok[g];
          if (tok >= 0) {
            float w = ew[g];
            float* op = &out[(size_t)tok * H_DIM + colv];
            f4 o = *(f4*)op;
            o.x += w * v.x; o.y += w * v.y; o.z += w * v.z; o.w += w * v.w;
            *(f4*)op = o;
          }
        }
      }
    }
  }
}

// ================= host =======================================================

extern "C" void kernel_launch(void* const* d_in, const int* in_sizes, int n_in,
                              void* d_out, int out_size, void* d_ws, size_t ws_size,
                              hipStream_t stream) {
  const float* x = (const float*)d_in[0];
  const float* sgw = (const float*)d_in[1];
  const float* suw = (const float*)d_in[2];
  const float* sdw = (const float*)d_in[3];
  const float* rgw = (const float*)d_in[4];
  const float* ruw = (const float*)d_in[5];
  const float* rdw = (const float*)d_in[6];
  const float* rw = (const float*)d_in[7];
  const float* rb = (const float*)d_in[8];
  float* out = (float*)d_out;
  char* ws = (char*)d_ws;

  const size_t o_xb = 0;                        // 37,748,736
  const size_t o_w = 37748736;
  const size_t w_sg = o_w;
  const size_t w_su = o_w + 589824;
  const size_t w_sd = o_w + 1179648;
  const size_t w_rg = o_w + 1769472;
  const size_t w_ru = o_w + 6488064;
  const size_t w_rd = o_w + 11206656;
  const size_t o_tki = o_w + 15925248;
  const size_t o_tkw = o_tki + 262144;
  const size_t o_meta = o_tkw + 262144;
  const size_t o_etok = o_meta + 8192;
  const size_t o_ew = o_etok + 270336;
  const size_t o_h = o_ew + 270336;             // 34,603,008
  // total 89,350,144 B

  unsigned short* xb = (unsigned short*)(ws + o_xb);
  int* tki = (int*)(ws + o_tki);
  float* tkw = (float*)(ws + o_tkw);
  int* counts = (int*)(ws + o_meta);
  int* cursor = counts + 512;
  int* offs16 = counts + 1024;
  int* pcnt16 = counts + 1040;
  int* pinfo = counts + 1056;
  int* etok = (int*)(ws + o_etok);
  float* ew = (float*)(ws + o_ew);
  unsigned short* h = (unsigned short*)(ws + o_h);

  unsigned short* wsg = (unsigned short*)(ws + w_sg);
  unsigned short* wsu = (unsigned short*)(ws + w_su);
  unsigned short* wsd = (unsigned short*)(ws + w_sd);
  unsigned short* wrg = (unsigned short*)(ws + w_rg);
  unsigned short* wru = (unsigned short*)(ws + w_ru);
  unsigned short* wrd = (unsigned short*)(ws + w_rd);

  hipMemsetAsync(ws + o_meta, 0, 8192, stream);
  hipMemsetAsync(etok, 0xFF, 270336, stream);
  hipMemsetAsync(ew, 0, 270336, stream);

  routercvt_k<<<256, 256, 0, stream>>>(x, xb, rw, rb, tki, tkw, counts);
  dim3 tb(32, 8);
  cvt_HI_k<<<dim3(16, 18, 18), tb, 0, stream>>>(sgw, suw, rgw, ruw, wsg, wsu, wrg, wru);
  cvt_IH_k<<<dim3(18, 16, 9), tb, 0, stream>>>(sdw, rdw, wsd, wrd);
  offsets_k<<<1, 64, 0, stream>>>(counts, offs16, pcnt16, pinfo);
  scatter_k<<<128, 256, 0, stream>>>(tki, tkw, offs16, cursor, etok, ew);

  // shared expert
  gateup_k<1><<<dim3(256, 4), 512, 0, stream>>>(
      xb, wsg, wsu, h, nullptr, nullptr, nullptr, nullptr, 0);
  down_k<0><<<dim3(256, 5), 512, 0, stream>>>(
      h, wsd, out, nullptr, nullptr, nullptr, nullptr, nullptr, 0);

  // routed experts: one gate/up + one down per k-phase (race-free RMW)
  for (int p = 0; p < 2; p++) {
    gateup_k<0><<<dim3(MAXMB, 4), 512, 0, stream>>>(
        xb, wrg, wru, h, etok, offs16, pcnt16, pinfo, p);
    down_k<1><<<dim3(MAXMB, 5), 512, 0, stream>>>(
        h, wrd, out, etok, ew, offs16, pcnt16, pinfo, p);
  }
}

// Round 8
// 344.719 us; speedup vs baseline: 2.0758x; 1.0968x over previous
//
#include <hip/hip_runtime.h>
#include <stdint.h>

#define T_TOK 32768
#define H_DIM 576
#define I_DIM 512
#define NEXP 8
#define WELEM 294912  // 576*512 elements per expert weight matrix

typedef __attribute__((ext_vector_type(8))) short short8;
typedef __attribute__((ext_vector_type(4))) float f32x4;
typedef __attribute__((ext_vector_type(4))) float f4;
typedef __attribute__((ext_vector_type(4))) unsigned short u16x4;

__device__ __forceinline__ unsigned short f2bf(float f) {
  union { float f; unsigned u; } v; v.f = f;
  unsigned r = (v.u + 0x7fffu + ((v.u >> 16) & 1u)) >> 16;
  return (unsigned short)r;
}

__device__ __forceinline__ void gl16(const void* g, void* l) {
  __builtin_amdgcn_global_load_lds(
      (const __attribute__((address_space(1))) unsigned*)g,
      (__attribute__((address_space(3))) unsigned*)l, 16, 0, 0);
}

// ============ fused router + x->bf16 convert (round-6 proven) ================
__global__ __launch_bounds__(256) void routercvt_k(
    const float* __restrict__ x, unsigned short* __restrict__ xb,
    const float* __restrict__ rw, const float* __restrict__ rb,
    int* __restrict__ tki, float* __restrict__ tkw, int* __restrict__ counts) {
  __shared__ float lrw[H_DIM * NEXP];
  __shared__ float tile[32][132];
  __shared__ float red[128][8];
  __shared__ int hist[16];
  int tid = threadIdx.x;
  for (int i = tid; i < 1152; i += 256)
    *(f4*)&lrw[i * 4] = *(const f4*)&rw[i * 4];
  if (tid < 16) hist[tid] = 0;
  int t0 = blockIdx.x * 128;
  int half = tid >> 7, tl = tid & 127;
  float acc[NEXP] = {};
  for (int c = 0; c < 18; c++) {
    __syncthreads();
#pragma unroll
    for (int k = 0; k < 4; k++) {
      int f = tid + k * 256;
      int rgrp = f >> 9, fl = f & 511;
      int tl2 = fl >> 2, seg = fl & 3;
      int h = (rgrp ? 288 : 0) + c * 16 + seg * 4;
      size_t gi = (size_t)(t0 + tl2) * H_DIM + h;
      f4 v = *(const f4*)(x + gi);
      u16x4 o;
      o.x = f2bf(v.x); o.y = f2bf(v.y); o.z = f2bf(v.z); o.w = f2bf(v.w);
      *(u16x4*)(xb + gi) = o;
      int row = rgrp * 16 + seg * 4;
      tile[row + 0][tl2] = v.x; tile[row + 1][tl2] = v.y;
      tile[row + 2][tl2] = v.z; tile[row + 3][tl2] = v.w;
    }
    __syncthreads();
    int hbase = half * 288 + c * 16;
    int rbase = half * 16;
#pragma unroll
    for (int hh = 0; hh < 16; hh++) {
      float xv = tile[rbase + hh][tl];
      f4 w0 = *(const f4*)&lrw[(hbase + hh) * 8];
      f4 w1 = *(const f4*)&lrw[(hbase + hh) * 8 + 4];
      acc[0] += xv * w0.x; acc[1] += xv * w0.y;
      acc[2] += xv * w0.z; acc[3] += xv * w0.w;
      acc[4] += xv * w1.x; acc[5] += xv * w1.y;
      acc[6] += xv * w1.z; acc[7] += xv * w1.w;
    }
  }
  if (half) {
#pragma unroll
    for (int e = 0; e < NEXP; e++) red[tl][e] = acc[e];
  }
  __syncthreads();
  if (!half) {
    int t = t0 + tl;
    float l[NEXP];
#pragma unroll
    for (int e = 0; e < NEXP; e++) l[e] = acc[e] + red[tl][e] + rb[e];
    int e0 = 0;
#pragma unroll
    for (int e = 1; e < NEXP; e++) if (l[e] > l[e0]) e0 = e;
    int e1 = -1;
#pragma unroll
    for (int e = 0; e < NEXP; e++) {
      if (e == e0) continue;
      if (e1 < 0 || l[e] > l[e1]) e1 = e;
    }
    float w0 = 1.f / (1.f + __expf(l[e1] - l[e0]));
    tki[t * 2] = e0; tki[t * 2 + 1] = e1;
    tkw[t * 2] = w0; tkw[t * 2 + 1] = 1.f - w0;
    atomicAdd(&hist[e0], 1);
    atomicAdd(&hist[8 + e1], 1);
  }
  __syncthreads();
  if (tid < 16) atomicAdd(&counts[tid * 32], hist[tid]);
}

// ============ merged weight transposes (round-7, index-verified) =============
__global__ void cvt_w_k(const float* __restrict__ sgw, const float* __restrict__ suw,
                        const float* __restrict__ rgw, const float* __restrict__ ruw,
                        const float* __restrict__ sdw, const float* __restrict__ rdw,
                        unsigned short* __restrict__ wsg, unsigned short* __restrict__ wsu,
                        unsigned short* __restrict__ wrg, unsigned short* __restrict__ wru,
                        unsigned short* __restrict__ wsd, unsigned short* __restrict__ wrd) {
  __shared__ float tile[32][33];
  int b = blockIdx.x;
  const float* src; unsigned short* dst;
  int C, bx, by;
  if (b < 5184) {
    int z = b / 288, r = b % 288;
    bx = r & 15; by = r >> 4; C = 512;
    if (z == 0)      { src = sgw;                            dst = wsg; }
    else if (z == 1) { src = suw;                            dst = wsu; }
    else if (z < 10) { src = rgw + (size_t)(z - 2) * WELEM;  dst = wrg + (size_t)(z - 2) * WELEM; }
    else             { src = ruw + (size_t)(z - 10) * WELEM; dst = wru + (size_t)(z - 10) * WELEM; }
  } else {
    int b2 = b - 5184;
    int z = b2 / 288, r = b2 % 288;
    bx = r % 18; by = r / 18; C = 576;
    src = (z == 0) ? sdw : rdw + (size_t)(z - 1) * WELEM;
    dst = (z == 0) ? wsd : wrd + (size_t)(z - 1) * WELEM;
  }
  int R = 1088 - C;
  int r0 = by * 32, c0 = bx * 32;
  for (int i = threadIdx.y; i < 32; i += 8)
    tile[i][threadIdx.x] = src[(size_t)(r0 + i) * C + c0 + threadIdx.x];
  __syncthreads();
  for (int i = threadIdx.y; i < 32; i += 8)
    dst[(size_t)(c0 + i) * R + r0 + threadIdx.x] = f2bf(tile[threadIdx.x][i]);
}

__global__ void offsets_k(const int* __restrict__ counts, int* __restrict__ offs16,
                          int* __restrict__ pcnt16, int* __restrict__ pinfo) {
  if (threadIdx.x == 0) {
    int o = 0;
    for (int s = 0; s < 16; s++) {
      int c = counts[s * 32];
      int pc = (c + 127) & ~127;
      offs16[s] = o; pcnt16[s] = pc;
      o += pc;
    }
    pinfo[0] = offs16[8];
    pinfo[1] = o - offs16[8];
  }
}

__global__ __launch_bounds__(256) void scatter_k(
    const int* __restrict__ tki, const float* __restrict__ tkw,
    const int* __restrict__ offs16, int* __restrict__ cursor /*stride 32*/,
    int* __restrict__ etok, float* __restrict__ ew) {
  __shared__ int hist[16], base[16], lcur[16];
  int tid = threadIdx.x;
  if (tid < 16) { hist[tid] = 0; lcur[tid] = 0; }
  __syncthreads();
  int t = blockIdx.x * 256 + tid;
  int s0 = tki[t * 2], s1 = 8 + tki[t * 2 + 1];
  atomicAdd(&hist[s0], 1);
  atomicAdd(&hist[s1], 1);
  __syncthreads();
  if (tid < 16) base[tid] = atomicAdd(&cursor[tid * 32], hist[tid]);
  __syncthreads();
#pragma unroll
  for (int k = 0; k < 2; k++) {
    int s = (k == 0) ? s0 : s1;
    int r = atomicAdd(&lcur[s], 1);
    int slot = offs16[s] + base[s] + r;
    etok[slot] = t;
    ew[slot] = tkw[t * 2 + k];
  }
}

// ---------------- fused gate/up GEMM + silu, XCD-chunked 1D grid -------------
// SHARED=1: identity rows [0,T). SHARED=0 merged=1: ALL padded rows (both
// phases), h indexed globally (h must have 67584 rows). SHARED=0 merged=0:
// phase p only, h indexed phase-locally.
template <int SHARED>
__global__ __launch_bounds__(512, 2) void gateup_k(
    const unsigned short* __restrict__ xb, const unsigned short* __restrict__ wg,
    const unsigned short* __restrict__ wu, unsigned short* __restrict__ h,
    const int* __restrict__ etok, const int* __restrict__ offs16,
    const int* __restrict__ pcnt16, const int* __restrict__ pinfo,
    int p, int merged, int mchunk) {
  int bid = blockIdx.x;
  int xcd = bid & 7, l = bid >> 3;
  int mb = xcd * mchunk + (l >> 2);
  int nb = l & 3;
  int nrows = SHARED ? T_TOK : (merged ? pinfo[0] + pinfo[1] : pinfo[p]);
  if (mb * 128 >= nrows) return;
  __shared__ unsigned short As[128 * 32];
  __shared__ unsigned short Bg[128 * 32];
  __shared__ unsigned short Bu[128 * 32];
  int t = threadIdx.x;
  int wv = t >> 6, lane = t & 63;
  int ar = t >> 2, seg = t & 3;
  int sg = seg ^ ((ar >> 1) & 3);
  int m0 = mb * 128 + ar;
  int tok0, e = 0;
  if (SHARED) {
    tok0 = m0;
  } else {
    int rl = (!merged && p) ? pinfo[0] : 0;
    int g = rl + m0;  // global padded-row index
    int s = 0;
#pragma unroll
    for (int i = 0; i < 15; i++) s += (g >= offs16[i] + pcnt16[i]) ? 1 : 0;
    e = s & 7;
    tok0 = etok[g];
    if (tok0 < 0) tok0 = 0;
  }
  const unsigned short* ga = xb + (size_t)tok0 * H_DIM + sg * 8;
  int n0 = nb * 128 + ar;
  const unsigned short* gg = wg + (size_t)e * WELEM + (size_t)n0 * H_DIM + sg * 8;
  const unsigned short* gu = wu + (size_t)e * WELEM + (size_t)n0 * H_DIM + sg * 8;
  char* lA = (char*)As + wv * 1024;
  char* lG = (char*)Bg + wv * 1024;
  char* lU = (char*)Bu + wv * 1024;
  int fr = lane & 15, fq = lane >> 4;
  int wm = (wv >> 2) * 64, wn = (wv & 3) * 32;
  f32x4 accg[4][2] = {};
  f32x4 accu[4][2] = {};
  for (int k0 = 0; k0 < H_DIM; k0 += 32) {
    gl16(ga + k0, lA);
    gl16(gg + k0, lG);
    gl16(gu + k0, lU);
    __syncthreads();
    short8 a[4], g[2], u[2];
#pragma unroll
    for (int i = 0; i < 4; i++) {
      int r = wm + i * 16 + fr;
      a[i] = *(const short8*)&As[r * 32 + (fq ^ ((r >> 1) & 3)) * 8];
    }
#pragma unroll
    for (int j = 0; j < 2; j++) {
      int r = wn + j * 16 + fr;
      int sw = (fq ^ ((r >> 1) & 3)) * 8;
      g[j] = *(const short8*)&Bg[r * 32 + sw];
      u[j] = *(const short8*)&Bu[r * 32 + sw];
    }
#pragma unroll
    for (int i = 0; i < 4; i++)
#pragma unroll
      for (int j = 0; j < 2; j++) {
        accg[i][j] = __builtin_amdgcn_mfma_f32_16x16x32_bf16(a[i], g[j], accg[i][j], 0, 0, 0);
        accu[i][j] = __builtin_amdgcn_mfma_f32_16x16x32_bf16(a[i], u[j], accu[i][j], 0, 0, 0);
      }
    __syncthreads();
  }
#pragma unroll
  for (int i = 0; i < 4; i++)
#pragma unroll
    for (int j = 0; j < 2; j++)
#pragma unroll
      for (int r = 0; r < 4; r++) {
        int row = mb * 128 + wm + i * 16 + fq * 4 + r;
        int col = nb * 128 + wn + j * 16 + fr;
        float gv = accg[i][j][r], uv = accu[i][j][r];
        float hv = (gv / (1.f + __expf(-gv))) * uv;
        h[(size_t)row * I_DIM + col] = f2bf(hv);
      }
}

// ---------------- down GEMM, staged epilogue, XCD-chunked 1D grid ------------
// MODE 0: shared (store). MODE 1: phase-p routed scatter RMW; h indexed
// globally when merged=1, phase-locally when merged=0.
template <int MODE>
__global__ __launch_bounds__(512, 2) void down_k(
    const unsigned short* __restrict__ hbuf, const unsigned short* __restrict__ wd,
    float* __restrict__ out, const int* __restrict__ etok, const float* __restrict__ ew,
    const int* __restrict__ offs16, const int* __restrict__ pcnt16,
    const int* __restrict__ pinfo, int p, int merged, int mchunk) {
  int bid = blockIdx.x;
  int xcd = bid & 7, l = bid >> 3;
  int mb = xcd * mchunk + l / 5;
  int nb = l % 5;
  int nrows = (MODE == 0) ? T_TOK : pinfo[p];
  if (mb * 128 >= nrows) return;
  int row_lo = (MODE == 1 && p == 1) ? pinfo[0] : 0;
  int hrow_lo = (MODE == 1 && merged) ? row_lo : 0;
  __shared__ unsigned short AB[2][128 * 32];
  int t = threadIdx.x;
  int wv = t >> 6, lane = t & 63;
  int ar = t >> 2, seg = t & 3;
  int sg = seg ^ ((ar >> 1) & 3);
  int e = 0;
  if (MODE == 1) {
    int g = row_lo + mb * 128 + ar;
    int s = 0;
#pragma unroll
    for (int i = 0; i < 15; i++) s += (g >= offs16[i] + pcnt16[i]) ? 1 : 0;
    e = s & 7;
  }
  const unsigned short* ga = hbuf + (size_t)(hrow_lo + mb * 128 + ar) * I_DIM + sg * 8;
  int n0 = nb * 128 + ar;
  if (n0 > H_DIM - 1) n0 = H_DIM - 1;
  const unsigned short* gb = wd + (size_t)e * WELEM + (size_t)n0 * I_DIM + sg * 8;
  char* lA = (char*)AB[0] + wv * 1024;
  char* lB = (char*)AB[1] + wv * 1024;
  int fr = lane & 15, fq = lane >> 4;
  int wm = (wv >> 2) * 64, wn = (wv & 3) * 32;
  f32x4 acc[4][2] = {};
  for (int k0 = 0; k0 < I_DIM; k0 += 32) {
    gl16(ga + k0, lA);
    gl16(gb + k0, lB);
    __syncthreads();
    short8 a[4], b2[2];
#pragma unroll
    for (int i = 0; i < 4; i++) {
      int r = wm + i * 16 + fr;
      a[i] = *(const short8*)&AB[0][r * 32 + (fq ^ ((r >> 1) & 3)) * 8];
    }
#pragma unroll
    for (int j = 0; j < 2; j++) {
      int r = wn + j * 16 + fr;
      b2[j] = *(const short8*)&AB[1][r * 32 + (fq ^ ((r >> 1) & 3)) * 8];
    }
#pragma unroll
    for (int i = 0; i < 4; i++)
#pragma unroll
      for (int j = 0; j < 2; j++)
        acc[i][j] = __builtin_amdgcn_mfma_f32_16x16x32_bf16(a[i], b2[j], acc[i][j], 0, 0, 0);
    __syncthreads();
  }
  // staged epilogue: 4 chunks of 32 rows x 128 cols fp32 (16 KB LDS reuse)
  float* st = (float*)AB;
  int q = t & 31;
  int colv = nb * 128 + q * 4;
  bool colok = colv < H_DIM;
#pragma unroll
  for (int c = 0; c < 4; c++) {
    __syncthreads();
    if ((wm == 64) == (c >= 2)) {
#pragma unroll
      for (int ii = 0; ii < 2; ii++) {
        int i = (c & 1) * 2 + ii;
#pragma unroll
        for (int j = 0; j < 2; j++)
#pragma unroll
          for (int r = 0; r < 4; r++)
            st[(ii * 16 + fq * 4 + r) * 128 + wn + j * 16 + fr] = acc[i][j][r];
      }
    }
    __syncthreads();
#pragma unroll
    for (int ps = 0; ps < 2; ps++) {
      int lr = (t >> 5) + ps * 16;
      int mloc = mb * 128 + c * 32 + lr;
      if (colok) {
        f4 v = *(f4*)&st[lr * 128 + q * 4];
        if (MODE == 0) {
          *(f4*)&out[(size_t)mloc * H_DIM + colv] = v;
        } else {
          int g = row_lo + mloc;
          int tok = etok[g];
          if (tok >= 0) {
            float w = ew[g];
            float* op = &out[(size_t)tok * H_DIM + colv];
            f4 o = *(f4*)op;
            o.x += w * v.x; o.y += w * v.y; o.z += w * v.z; o.w += w * v.w;
            *(f4*)op = o;
          }
        }
      }
    }
  }
}

// ================= host =======================================================

extern "C" void kernel_launch(void* const* d_in, const int* in_sizes, int n_in,
                              void* d_out, int out_size, void* d_ws, size_t ws_size,
                              hipStream_t stream) {
  const float* x = (const float*)d_in[0];
  const float* sgw = (const float*)d_in[1];
  const float* suw = (const float*)d_in[2];
  const float* sdw = (const float*)d_in[3];
  const float* rgw = (const float*)d_in[4];
  const float* ruw = (const float*)d_in[5];
  const float* rdw = (const float*)d_in[6];
  const float* rw = (const float*)d_in[7];
  const float* rb = (const float*)d_in[8];
  float* out = (float*)d_out;
  char* ws = (char*)d_ws;

  const size_t o_xb = 0;
  const size_t o_w = 37748736;
  const size_t w_sg = o_w;
  const size_t w_su = o_w + 589824;
  const size_t w_sd = o_w + 1179648;
  const size_t w_rg = o_w + 1769472;
  const size_t w_ru = o_w + 6488064;
  const size_t w_rd = o_w + 11206656;
  const size_t o_tki = o_w + 15925248;
  const size_t o_tkw = o_tki + 262144;
  const size_t o_meta = o_tkw + 262144;
  const size_t o_etok = o_meta + 8192;
  const size_t o_ew = o_etok + 270336;
  const size_t o_h = o_ew + 270336;             // 54,747,136
  // merged: h = 67584 rows * 1024 B = 69,206,016 -> total 123,953,152
  // fallback: h = 33792 rows -> total 89,350,144
  const size_t need_merged = o_h + (size_t)67584 * 1024;

  unsigned short* xb = (unsigned short*)(ws + o_xb);
  int* tki = (int*)(ws + o_tki);
  float* tkw = (float*)(ws + o_tkw);
  int* counts = (int*)(ws + o_meta);
  int* cursor = counts + 512;
  int* offs16 = counts + 1024;
  int* pcnt16 = counts + 1040;
  int* pinfo = counts + 1056;
  int* etok = (int*)(ws + o_etok);
  float* ew = (float*)(ws + o_ew);
  unsigned short* h = (unsigned short*)(ws + o_h);
  int merged = (ws_size >= need_merged) ? 1 : 0;

  unsigned short* wsg = (unsigned short*)(ws + w_sg);
  unsigned short* wsu = (unsigned short*)(ws + w_su);
  unsigned short* wsd = (unsigned short*)(ws + w_sd);
  unsigned short* wrg = (unsigned short*)(ws + w_rg);
  unsigned short* wru = (unsigned short*)(ws + w_ru);
  unsigned short* wrd = (unsigned short*)(ws + w_rd);

  hipMemsetAsync(ws + o_meta, 0, 8192, stream);
  hipMemsetAsync(etok, 0xFF, 270336, stream);  // pad tokens = -1 (ew pads never read)

  routercvt_k<<<256, 256, 0, stream>>>(x, xb, rw, rb, tki, tkw, counts);
  cvt_w_k<<<7776, dim3(32, 8), 0, stream>>>(sgw, suw, rgw, ruw, sdw, rdw,
                                            wsg, wsu, wrg, wru, wsd, wrd);
  offsets_k<<<1, 64, 0, stream>>>(counts, offs16, pcnt16, pinfo);
  scatter_k<<<128, 256, 0, stream>>>(tki, tkw, offs16, cursor, etok, ew);

  // shared expert
  gateup_k<1><<<1024, 512, 0, stream>>>(xb, wsg, wsu, h, nullptr, nullptr,
                                        nullptr, nullptr, 0, 0, 32);
  down_k<0><<<1280, 512, 0, stream>>>(h, wsd, out, nullptr, nullptr, nullptr,
                                      nullptr, nullptr, 0, 0, 32);

  if (merged) {
    // ONE gate/up over all 67568 padded rows (528 mb-blocks, xcd-chunk 66)
    gateup_k<0><<<2112, 512, 0, stream>>>(xb, wrg, wru, h, etok, offs16,
                                          pcnt16, pinfo, 0, 1, 66);
    down_k<1><<<1320, 512, 0, stream>>>(h, wrd, out, etok, ew, offs16,
                                        pcnt16, pinfo, 0, 1, 33);
    down_k<1><<<1320, 512, 0, stream>>>(h, wrd, out, etok, ew, offs16,
                                        pcnt16, pinfo, 1, 1, 33);
  } else {
    // per-phase (round-6 proven semantics, h phase-local)
    for (int p = 0; p < 2; p++) {
      gateup_k<0><<<1056, 512, 0, stream>>>(xb, wrg, wru, h, etok, offs16,
                                            pcnt16, pinfo, p, 0, 33);
      down_k<1><<<1320, 512, 0, stream>>>(h, wrd, out, etok, ew, offs16,
                                          pcnt16, pinfo, p, 0, 33);
    }
  }
}